// Round 8
// baseline (499.646 us; speedup 1.0000x reference)
//
#include <hip/hip_runtime.h>

typedef __bf16 bf16x8 __attribute__((ext_vector_type(8)));
typedef float f32x4 __attribute__((ext_vector_type(4)));

__device__ __forceinline__ unsigned short f2bf(float f) {
  unsigned u = __builtin_bit_cast(unsigned, f);
  u += 0x7FFF + ((u >> 16) & 1);   // RNE
  return (unsigned short)(u >> 16);
}
__device__ __forceinline__ float h2f(unsigned short h) {
  return (float)__builtin_bit_cast(_Float16, h);
}
__device__ __forceinline__ unsigned short f2h(float f) {
  return __builtin_bit_cast(unsigned short, (_Float16)f);
}

__device__ __forceinline__ void gload_lds16(const void* g, void* l) {
  __builtin_amdgcn_global_load_lds(
      (const __attribute__((address_space(1))) void*)g,
      (__attribute__((address_space(3))) void*)l, 16, 0, 0);
}

// ---------------------------------------------------------------------------
// 128x128 tile GEMM (m97-proven config: 256 thr, 4 waves 2x2, single 32KB LDS
// buffer, plain syncthreads loop, 3-4 blocks/CU for cross-block overlap).
// C = A @ Bt^T, bf16 MFMA 16x16x32, fp32 acc, XOR-swizzled LDS (conflict-free
// ds_read_b128), bijective XCD-swizzled 1D grid.
// ASRC 0: A bf16 (global_load_lds staging).
// ASRC 1: A fp32 (reg-staged: 8x float4 load -> RNE cvt -> 4x ds_write_b128
//         at swizzled offsets) — fuses the fp32->bf16 conversion pass.
// OUTMODE 0: fp32 + bias[col]; 2: fp32 split-K partial (slice zt);
//         3: fp16 exp(acc + bias[col]) (fused softmax numerator).
// ---------------------------------------------------------------------------
template <int ASRC, int OUTMODE>
__global__ __launch_bounds__(256, 3) void gemmf(
    const void* __restrict__ Av, const unsigned short* __restrict__ Bt,
    void* __restrict__ Cv, const float* __restrict__ bias,
    int N, int K, int ldk, int gx, int gy, int nsplit,
    long sA, long sB, long sC)
{
  __shared__ alignas(16) unsigned char smem[32768];  // A 16KB | B 16KB
  const int tid  = threadIdx.x;
  const int lane = tid & 63;
  const int wave = tid >> 6;
  const int waveM = wave >> 1;      // 0..1
  const int waveN = wave & 1;       // 0..1

  // bijective XCD swizzle (nwg % 8 == 0 for all launches here)
  const int nwg = (int)gridDim.x;
  const int cpx = nwg >> 3;
  const int wg  = (int)blockIdx.x;
  const int w   = (wg & 7) * cpx + (wg >> 3);
  const int x   = w % gx;
  const int rem = w / gx;
  const int y   = rem % gy;
  const int zt  = rem / gy;
  const int bz  = zt / nsplit;
  const int sp  = zt % nsplit;

  const int m0 = y * 128, n0 = x * 128;
  const size_t ldkB  = (size_t)ldk * 2;
  const size_t ldkB32 = ldkB * 32;
  const long es = (ASRC == 1) ? 4 : 2;
  const char* Abase = (const char*)Av + ((long)bz * sA + (long)sp * K) * es
                      + (size_t)m0 * (size_t)ldk * es;
  const char* Bbase = (const char*)Bt + ((long)bz * sB + (long)sp * K) * 2
                      + (size_t)n0 * ldkB;

  // staging addresses
  const int srow = tid >> 3;                       // 0..31
  const int scol = ((tid * 16) & 127) ^ ((srow & 7) << 4);
  const char* ApR = Abase + (size_t)srow * ldkB + scol;   // ASRC==0
  const char* BpR = Bbase + (size_t)srow * ldkB + scol;
  const unsigned oA0 = (unsigned)tid * 16;

  // ASRC==1: thread t -> row r=t>>1, k-half h=t&1 (32 floats -> 32 bf16)
  const char* Ap32 = Abase + (size_t)(tid >> 1) * (size_t)ldk * 4 + (size_t)(tid & 1) * 128;
  int dso[4];
  {
    const int r = tid >> 1, h = tid & 1, sw = (r & 7) << 4;
#pragma unroll
    for (int u = 0; u < 4; ++u) dso[u] = r * 128 + ((64 * h + 16 * u) ^ sw);
  }

  // ds_read fragment offsets (kk=0); kk=1 is ^64 (swizzle field bits 4-6)
  int offA[4], offB[4];
  {
    const int q16 = (lane >> 4) << 4;
#pragma unroll
    for (int mi = 0; mi < 4; ++mi) {
      const int r = waveM * 64 + mi * 16 + (lane & 15);
      offA[mi] = r * 128 + (q16 ^ ((r & 7) << 4));
    }
#pragma unroll
    for (int ni = 0; ni < 4; ++ni) {
      const int r = waveN * 64 + ni * 16 + (lane & 15);
      offB[ni] = 16384 + r * 128 + (q16 ^ ((r & 7) << 4));
    }
  }

  f32x4 acc[4][4] = {};

  const int nk = K >> 6;
  for (int kt = 0; kt < nk; ++kt) {
    const size_t kb = (size_t)kt << 7;             // bf16 bytes per K-tile
    if (ASRC == 0) {
#pragma unroll
      for (int j = 0; j < 4; ++j)
        gload_lds16(ApR + j * ldkB32 + kb, smem + oA0 + j * 4096);
    } else {
      const char* s = Ap32 + ((size_t)kt << 8);    // fp32 bytes per K-tile
      float4 fv[8];
#pragma unroll
      for (int u = 0; u < 8; ++u) fv[u] = *(const float4*)(s + u * 16);
#pragma unroll
      for (int u = 0; u < 4; ++u) {
        unsigned short hw[8];
        const float* f0 = (const float*)&fv[2 * u];
        const float* f1 = (const float*)&fv[2 * u + 1];
#pragma unroll
        for (int e = 0; e < 4; ++e) { hw[e] = f2bf(f0[e]); hw[4 + e] = f2bf(f1[e]); }
        *(uint4*)&smem[dso[u]] = *(const uint4*)hw;
      }
    }
#pragma unroll
    for (int j = 0; j < 4; ++j)
      gload_lds16(BpR + j * ldkB32 + kb, smem + 16384 + oA0 + j * 4096);
    __syncthreads();
#pragma unroll
    for (int kk = 0; kk < 2; ++kk) {
      const int kx = kk << 6;
      bf16x8 aF[4], bF[4];
#pragma unroll
      for (int mi = 0; mi < 4; ++mi) aF[mi] = *(const bf16x8*)&smem[offA[mi] ^ kx];
#pragma unroll
      for (int ni = 0; ni < 4; ++ni) bF[ni] = *(const bf16x8*)&smem[offB[ni] ^ kx];
#pragma unroll
      for (int mi = 0; mi < 4; ++mi)
#pragma unroll
        for (int ni = 0; ni < 4; ++ni)
          acc[mi][ni] = __builtin_amdgcn_mfma_f32_16x16x32_bf16(aF[mi], bF[ni], acc[mi][ni], 0, 0, 0);
    }
    __syncthreads();
  }

  // epilogue
  const int rb = (lane >> 4) * 4;
  const int cb_ = lane & 15;
  const long zout = (OUTMODE == 2) ? (long)zt : (long)bz;
#pragma unroll
  for (int m = 0; m < 4; ++m) {
#pragma unroll
    for (int n = 0; n < 4; ++n) {
      const int col = n0 + waveN * 64 + n * 16 + cb_;
      const float badd = (OUTMODE == 0 || OUTMODE == 3) ? bias[col] : 0.f;
#pragma unroll
      for (int r = 0; r < 4; ++r) {
        const int row = m0 + waveM * 64 + m * 16 + rb + r;
        const float vv = acc[m][n][r] + badd;
        if (OUTMODE == 3)
          ((unsigned short*)Cv)[zout * sC + (size_t)row * N + col] = f2h(__expf(vv));
        else
          ((float*)Cv)[zout * sC + (size_t)row * N + col] = vv;
      }
    }
  }
}

// ---------------------------------------------------------------------------
// split-K x2 reduce: out[b][i] = bf16(P[b*2][i] + P[b*2+1][i])
// ---------------------------------------------------------------------------
__global__ __launch_bounds__(256) void red2(
    const float* __restrict__ P, unsigned short* __restrict__ O)
{
  const int i = blockIdx.x * 256 + threadIdx.x;
  const int b = i >> 18;
  const int j = i & 262143;
  const float4 v0 = ((const float4*)(P + (((long)(b * 2 + 0)) << 20)))[j];
  const float4 v1 = ((const float4*)(P + (((long)(b * 2 + 1)) << 20)))[j];
  unsigned short o4[4] = {f2bf(v0.x + v1.x), f2bf(v0.y + v1.y),
                          f2bf(v0.z + v1.z), f2bf(v0.w + v1.w)};
  ((uint2*)(O + ((long)b << 20)))[j] = *(const uint2*)o4;
}

// ---------------------------------------------------------------------------
// Row normalize of E=exp(S): Qp = E / rowsum(E), fp16 in -> bf16 out.
// ---------------------------------------------------------------------------
__global__ __launch_bounds__(256) void row_norm_e(
    const unsigned short* __restrict__ E, unsigned short* __restrict__ O)
{
  const int row = blockIdx.x;
  const int tid = threadIdx.x;
  const uint2 u = ((const uint2*)(E + (size_t)row * 1024))[tid];
  const float e0 = h2f((unsigned short)(u.x & 0xffff));
  const float e1 = h2f((unsigned short)(u.x >> 16));
  const float e2 = h2f((unsigned short)(u.y & 0xffff));
  const float e3 = h2f((unsigned short)(u.y >> 16));
  float s = (e0 + e1) + (e2 + e3);
#pragma unroll
  for (int o = 32; o >= 1; o >>= 1) s += __shfl_xor(s, o);
  __shared__ float rs[4];
  if ((tid & 63) == 0) rs[tid >> 6] = s;
  __syncthreads();
  s = (rs[0] + rs[1]) + (rs[2] + rs[3]);
  const float inv = 1.f / s;
  unsigned short o4[4] = {f2bf(e0 * inv), f2bf(e1 * inv), f2bf(e2 * inv), f2bf(e3 * inv)};
  ((uint2*)(O + (size_t)row * 1024))[tid] = *(const uint2*)o4;
}

// ---------------------------------------------------------------------------
// Column partial sums of E (fp16), 8-deep ILP. grid (D/256, L/64, B).
// ---------------------------------------------------------------------------
__global__ __launch_bounds__(256) void col_sum_e(
    const unsigned short* __restrict__ E, float* __restrict__ psum)
{
  const int d = blockIdx.x * 256 + threadIdx.x;
  const int slab = blockIdx.y;
  const int b = blockIdx.z;
  const unsigned short* p = E + ((size_t)b * 4096 + (size_t)slab * 64) * 1024 + d;
  float acc[8] = {};
#pragma unroll
  for (int i = 0; i < 8; ++i) {
    unsigned short x[8];
#pragma unroll
    for (int j = 0; j < 8; ++j) x[j] = p[(size_t)(i * 8 + j) * 1024];
#pragma unroll
    for (int j = 0; j < 8; ++j) acc[j] += h2f(x[j]);
  }
  const float s = ((acc[0] + acc[1]) + (acc[2] + acc[3])) +
                  ((acc[4] + acc[5]) + (acc[6] + acc[7]));
  psum[((size_t)b * 64 + slab) * 1024 + d] = s;
}

__global__ __launch_bounds__(256) void col_inv(
    const float* __restrict__ psum, float* __restrict__ si)
{
  const int d = blockIdx.x * 256 + threadIdx.x;
  const int b = blockIdx.y;
  float s = 0.f;
#pragma unroll
  for (int i = 0; i < 64; ++i) s += psum[((size_t)b * 64 + i) * 1024 + d];
  si[b * 1024 + d] = 1.f / s;
}

// ---------------------------------------------------------------------------
// Column normalize + transpose: T[b][d][l] = bf16(E[b][l][d] * sinv[d])
// ---------------------------------------------------------------------------
__global__ __launch_bounds__(256) void col_norm_tr_e(
    const unsigned short* __restrict__ E, const float* __restrict__ sinv,
    unsigned short* __restrict__ T)
{
  __shared__ unsigned short tile[64][73];
  __shared__ float sl[64];
  const int l0 = blockIdx.x * 64;
  const int d0 = blockIdx.y * 64;
  const int b  = blockIdx.z;
  const int tid = threadIdx.x;
  if (tid < 64) sl[tid] = sinv[b * 1024 + d0 + tid];
  __syncthreads();
  const int r = tid >> 2;
  const int cq = (tid & 3) * 16;
  const unsigned short* Eb = E + ((size_t)b * 4096 + l0 + r) * 1024 + d0;
#pragma unroll
  for (int i = 0; i < 4; ++i) {
    const int c = cq + i * 4;
    const uint2 u = *(const uint2*)&Eb[c];
    tile[r][c + 0] = f2bf(h2f((unsigned short)(u.x & 0xffff)) * sl[c + 0]);
    tile[r][c + 1] = f2bf(h2f((unsigned short)(u.x >> 16))    * sl[c + 1]);
    tile[r][c + 2] = f2bf(h2f((unsigned short)(u.y & 0xffff)) * sl[c + 2]);
    tile[r][c + 3] = f2bf(h2f((unsigned short)(u.y >> 16))    * sl[c + 3]);
  }
  __syncthreads();
  const int c = tid >> 2;
  const int rq = (tid & 3) * 16;
  unsigned short outv[16];
#pragma unroll
  for (int j = 0; j < 16; ++j) outv[j] = tile[rq + j][c];
  unsigned short* Tb = T + ((size_t)b * 1024 + d0 + c) * 4096 + l0 + rq;
  ((uint4*)Tb)[0] = ((const uint4*)outv)[0];
  ((uint4*)Tb)[1] = ((const uint4*)outv)[1];
}

// ---------------------------------------------------------------------------
__global__ __launch_bounds__(256) void w_tr(
    const float* __restrict__ W, unsigned short* __restrict__ WT)
{
  __shared__ unsigned short tile[64][73];
  const int c0 = blockIdx.x * 64;
  const int r0 = blockIdx.y * 64;
  const int tid = threadIdx.x;
  const int r = tid >> 2;
  const int cq = (tid & 3) * 16;
#pragma unroll
  for (int i = 0; i < 4; ++i) {
    const int c = cq + i * 4;
    const float4 v = *(const float4*)&W[(size_t)(r0 + r) * 1024 + c0 + c];
    tile[r][c + 0] = f2bf(v.x);
    tile[r][c + 1] = f2bf(v.y);
    tile[r][c + 2] = f2bf(v.z);
    tile[r][c + 3] = f2bf(v.w);
  }
  __syncthreads();
  const int c = tid >> 2;
  const int rq = (tid & 3) * 16;
  unsigned short outv[16];
#pragma unroll
  for (int j = 0; j < 16; ++j) outv[j] = tile[rq + j][c];
  unsigned short* Tb = WT + (size_t)(c0 + c) * 1024 + r0 + rq;
  ((uint4*)Tb)[0] = ((const uint4*)outv)[0];
  ((uint4*)Tb)[1] = ((const uint4*)outv)[1];
}

// ---------------------------------------------------------------------------
extern "C" void kernel_launch(void* const* d_in, const int* in_sizes, int n_in,
                              void* d_out, int out_size, void* d_ws, size_t ws_size,
                              hipStream_t stream) {
  const float* q  = (const float*)d_in[0];
  const float* k  = (const float*)d_in[1];
  const float* v  = (const float*)d_in[2];
  const float* Wq = (const float*)d_in[3];
  const float* bq = (const float*)d_in[4];
  const float* Wk = (const float*)d_in[5];
  const float* bk = (const float*)d_in[6];
  const float* Wv = (const float*)d_in[7];
  const float* bv = (const float*)d_in[8];
  const float* Wo = (const float*)d_in[9];
  const float* bo = (const float*)d_in[10];
  float* out = (float*)d_out;

  // workspace layout
  char* p = (char*)d_ws;
  unsigned short* Mreg = (unsigned short*)p;  p += 33554432;      // Mbf + GTbf region
  unsigned short* WqT = (unsigned short*)p;  p += 2097152;
  unsigned short* WkT = (unsigned short*)p;  p += 2097152;
  unsigned short* WvT = (unsigned short*)p;  p += 2097152;
  unsigned short* WoT = (unsigned short*)p;  p += 2097152;
  char* Sreg = p;                            p += 67108864;       // E fp16 [16384][1024]; later split-K partials fp32 [8][1024][1024]
  unsigned short* E = (unsigned short*)Sreg;
  float* Part = (float*)Sreg;                                     // alias (E dead when Part written)
  unsigned short* Mbf = Mreg;                                     // [B][1024][1024]
  unsigned short* GTbf = Mreg + 4L * 1024 * 1024;                 // [B][1024][1024]
  unsigned short* Qp  = (unsigned short*)p;  p += 33554432;
  unsigned short* KpT = (unsigned short*)p;  p += 33554432;       // [B][1024][4096]
  unsigned short* VpT = (unsigned short*)p;  p += 33554432;
  float* psum = (float*)p; p += 4 * 64 * 1024 * 4;
  float* sinv = (float*)p; p += 4 * 1024 * 4;

  const dim3 blk(256);

  // weights -> bf16 transposed
  w_tr<<<dim3(16, 16), blk, 0, stream>>>(Wq, WqT);
  w_tr<<<dim3(16, 16), blk, 0, stream>>>(Wk, WkT);
  w_tr<<<dim3(16, 16), blk, 0, stream>>>(Wv, WvT);
  w_tr<<<dim3(16, 16), blk, 0, stream>>>(Wo, WoT);

  // ---- Q path: E = exp(q@Wq + bq) (fp32 A, fused cvt) ; Qp = E / rowsum
  gemmf<1, 3><<<1024, blk, 0, stream>>>(q, WqT, E, bq, 1024, 1024, 1024, 8, 128, 1, 0, 0, 0);
  row_norm_e<<<16384, blk, 0, stream>>>(E, Qp);

  // ---- K path
  gemmf<1, 3><<<1024, blk, 0, stream>>>(k, WkT, E, bk, 1024, 1024, 1024, 8, 128, 1, 0, 0, 0);
  col_sum_e<<<dim3(4, 64, 4), blk, 0, stream>>>(E, psum);
  col_inv<<<dim3(4, 4), blk, 0, stream>>>(psum, sinv);
  col_norm_tr_e<<<dim3(64, 16, 4), blk, 0, stream>>>(E, sinv, KpT);

  // ---- V path
  gemmf<1, 3><<<1024, blk, 0, stream>>>(v, WvT, E, bv, 1024, 1024, 1024, 8, 128, 1, 0, 0, 0);
  col_sum_e<<<dim3(4, 64, 4), blk, 0, stream>>>(E, psum);
  col_inv<<<dim3(4, 4), blk, 0, stream>>>(psum, sinv);
  col_norm_tr_e<<<dim3(64, 16, 4), blk, 0, stream>>>(E, sinv, VpT);

  // ---- M_b = Kp^T Vp : split-K x2 (chunks of 2048), P[b*2+s] = KpT@VpT^T
  gemmf<0, 2><<<512, blk, 0, stream>>>(KpT, VpT, Part, nullptr,
      1024, 2048, 4096, 8, 8, 2, 1024L * 4096, 1024L * 4096, 1024L * 1024);
  red2<<<4096, blk, 0, stream>>>(Part, Mbf);

  // ---- GT_b = (M_b @ Wo)^T = WoT @ M_b^T : split-K x2 over K=1024
  gemmf<0, 2><<<512, blk, 0, stream>>>(WoT, Mbf, Part, nullptr,
      1024, 512, 1024, 8, 8, 2, 0, 1024L * 1024, 1024L * 1024);
  red2<<<4096, blk, 0, stream>>>(Part, GTbf);

  // ---- Out_b = Qp_b @ GT_b^T + bo
  gemmf<0, 0><<<1024, blk, 0, stream>>>(Qp, GTbf, out, bo,
      1024, 1024, 1024, 8, 32, 1, 4096L * 1024, 1024L * 1024, 4096L * 1024);

  (void)in_sizes; (void)n_in; (void)out_size; (void)ws_size;
}

// Round 9
// 325.417 us; speedup vs baseline: 1.5354x; 1.5354x over previous
//
#include <hip/hip_runtime.h>

typedef _Float16 f16x8 __attribute__((ext_vector_type(8)));
typedef float f32x4 __attribute__((ext_vector_type(4)));

__device__ __forceinline__ float h2f(unsigned short h) {
  return (float)__builtin_bit_cast(_Float16, h);
}
__device__ __forceinline__ unsigned short f2h(float f) {
  return __builtin_bit_cast(unsigned short, (_Float16)f);
}

__device__ __forceinline__ void gload_lds16(const void* g, void* l) {
  __builtin_amdgcn_global_load_lds(
      (const __attribute__((address_space(1))) void*)g,
      (__attribute__((address_space(3))) void*)l, 16, 0, 0);
}

// ---------------------------------------------------------------------------
// 128x256 tile GEMM, C = A @ Bt^T (fp16 in, fp32 acc) — round-7 proven core:
// single 48KB LDS buffer, 8 waves (2M x 4N), plain syncthreads loop,
// XOR-swizzled LDS (conflict-free ds_read_b128), XCD-swizzled 1D grid.
// OUTMODE 0: fp32 + bias[col]
//         2: fp16 split-K partial (slice zt), no bias
//         3: fp16 exp(acc + bias[col]), normal [row][col] layout (Q path)
//         4: fp16 exp(acc + bias[col]), TRANSPOSED: ET[col][row], packed 8B
//         5: fp32 acc*sinv[row] + bias[col]  (fused row-softmax + out)
// ---------------------------------------------------------------------------
template <int OUTMODE>
__global__ __launch_bounds__(512, 4) void gemmt(
    const unsigned short* __restrict__ A, const unsigned short* __restrict__ Bt,
    void* __restrict__ Cv, const float* __restrict__ bias,
    const float* __restrict__ sinv,
    int N, int K, int ldk, int gx, int gy, int nsplit,
    long sA, long sB, long sC)
{
  __shared__ alignas(16) unsigned char smem[49152];  // A 16KB | B 32KB
  const int tid  = threadIdx.x;
  const int lane = tid & 63;
  const int wave = tid >> 6;
  const int waveM = wave >> 2;      // 0..1 (64 rows each)
  const int waveN = wave & 3;       // 0..3 (64 cols each)

  // bijective XCD swizzle (nwg % 8 == 0 for all launches here)
  const int nwg = (int)gridDim.x;
  const int cpx = nwg >> 3;
  const int wg  = (int)blockIdx.x;
  const int w   = (wg & 7) * cpx + (wg >> 3);
  const int x   = w % gx;
  const int rem = w / gx;
  const int y   = rem % gy;
  const int zt  = rem / gy;
  const int bz  = zt / nsplit;
  const int sp  = zt % nsplit;

  const int m0 = y * 128, n0 = x * 256;
  const size_t ldkB = (size_t)ldk * 2;
  const size_t ldkB64 = ldkB * 64, ldkB128 = ldkB * 128;

  // staging: LDS dst linear (tid*16); src inverse-swizzled
  const char* ApR;
  const char* BpR;
  {
    const char* Ab = (const char*)(A + (long)bz * sA + (long)sp * K) + (size_t)m0 * ldkB;
    const char* Bb = (const char*)(Bt + (long)bz * sB + (long)sp * K) + (size_t)n0 * ldkB;
    const int srow = tid >> 3;                       // 0..63
    const int scol = ((tid * 16) & 127) ^ ((srow & 7) << 4);
    ApR = Ab + (size_t)srow * ldkB + scol;
    BpR = Bb + (size_t)srow * ldkB + scol;
  }
  const unsigned oA0 = (unsigned)tid * 16;

  // ds_read byte offsets (kk=0); kk=1 offset = kk0 ^ 64 (bits 4-6 swizzle field)
  int offA[4], offB[4];
  {
    const int q16 = (lane >> 4) << 4;
#pragma unroll
    for (int mi = 0; mi < 4; ++mi) {
      const int r = waveM * 64 + mi * 16 + (lane & 15);
      offA[mi] = r * 128 + (q16 ^ ((r & 7) << 4));
    }
#pragma unroll
    for (int ni = 0; ni < 4; ++ni) {
      const int r = waveN * 64 + ni * 16 + (lane & 15);
      offB[ni] = 16384 + r * 128 + (q16 ^ ((r & 7) << 4));
    }
  }

  f32x4 acc[4][4] = {};

  const int nk = K >> 6;
  for (int kt = 0; kt < nk; ++kt) {
    const size_t kb = (size_t)kt * 128;
    gload_lds16(ApR + kb,                     smem + oA0);
    gload_lds16(ApR + ldkB64 + kb,            smem + oA0 + 8192);
    gload_lds16(BpR + kb,                     smem + 16384 + oA0);
    gload_lds16(BpR + ldkB64 + kb,            smem + 16384 + oA0 + 8192);
    gload_lds16(BpR + ldkB128 + kb,           smem + 16384 + oA0 + 16384);
    gload_lds16(BpR + ldkB128 + ldkB64 + kb,  smem + 16384 + oA0 + 24576);
    __syncthreads();
#pragma unroll
    for (int kk = 0; kk < 2; ++kk) {
      const int kx = kk << 6;
      f16x8 aF[4], bF[4];
#pragma unroll
      for (int mi = 0; mi < 4; ++mi) aF[mi] = *(const f16x8*)&smem[offA[mi] ^ kx];
#pragma unroll
      for (int ni = 0; ni < 4; ++ni) bF[ni] = *(const f16x8*)&smem[offB[ni] ^ kx];
#pragma unroll
      for (int mi = 0; mi < 4; ++mi)
#pragma unroll
        for (int ni = 0; ni < 4; ++ni)
          acc[mi][ni] = __builtin_amdgcn_mfma_f32_16x16x32_f16(aF[mi], bF[ni], acc[mi][ni], 0, 0, 0);
    }
    __syncthreads();
  }

  // epilogue
  const int rb = (lane >> 4) * 4;
  const int cb_ = lane & 15;
  const long zout = (OUTMODE == 2) ? (long)zt : (long)bz;
#pragma unroll
  for (int m = 0; m < 4; ++m) {
#pragma unroll
    for (int n = 0; n < 4; ++n) {
      const int col = n0 + waveN * 64 + n * 16 + cb_;
      const int row0 = m0 + waveM * 64 + m * 16 + rb;
      if (OUTMODE == 4) {
        const float badd = bias[col];
        unsigned short o4[4];
#pragma unroll
        for (int r = 0; r < 4; ++r) o4[r] = f2h(__expf(acc[m][n][r] + badd));
        *(uint2*)((unsigned short*)Cv + zout * sC + ((size_t)col << 12) + row0) =
            *(const uint2*)o4;
      } else if (OUTMODE == 3) {
        const float badd = bias[col];
#pragma unroll
        for (int r = 0; r < 4; ++r)
          ((unsigned short*)Cv)[zout * sC + (size_t)(row0 + r) * N + col] =
              f2h(__expf(acc[m][n][r] + badd));
      } else if (OUTMODE == 2) {
#pragma unroll
        for (int r = 0; r < 4; ++r)
          ((unsigned short*)Cv)[zout * sC + (size_t)(row0 + r) * N + col] = f2h(acc[m][n][r]);
      } else if (OUTMODE == 5) {
        const float badd = bias[col];
        const float4 sv4 = *(const float4*)&sinv[zout * 4096 + row0];
        const float* svp = (const float*)&sv4;
#pragma unroll
        for (int r = 0; r < 4; ++r)
          ((float*)Cv)[zout * sC + (size_t)(row0 + r) * N + col] = acc[m][n][r] * svp[r] + badd;
      } else {
        const float badd = bias[col];
#pragma unroll
        for (int r = 0; r < 4; ++r)
          ((float*)Cv)[zout * sC + (size_t)(row0 + r) * N + col] = acc[m][n][r] + badd;
      }
    }
  }
}

// ---------------------------------------------------------------------------
// fp32 -> fp16 convert (vectorized)
// ---------------------------------------------------------------------------
__global__ __launch_bounds__(256) void conv_h(
    const float* __restrict__ in, unsigned short* __restrict__ out, int n4)
{
  int i = blockIdx.x * 256 + threadIdx.x;
  if (i < n4) {
    float4 v = ((const float4*)in)[i];
    unsigned short o4[4] = {f2h(v.x), f2h(v.y), f2h(v.z), f2h(v.w)};
    ((uint2*)out)[i] = *(const uint2*)o4;
  }
}

// ---------------------------------------------------------------------------
// Weight transpose + fp16: WT[c][r] = f16(W[r][c]), 1024x1024
// ---------------------------------------------------------------------------
__global__ __launch_bounds__(256) void w_trh(
    const float* __restrict__ W, unsigned short* __restrict__ WT)
{
  __shared__ unsigned short tile[64][73];
  const int c0 = blockIdx.x * 64;
  const int r0 = blockIdx.y * 64;
  const int tid = threadIdx.x;
  const int r = tid >> 2;
  const int cq = (tid & 3) * 16;
#pragma unroll
  for (int i = 0; i < 4; ++i) {
    const int c = cq + i * 4;
    const float4 v = *(const float4*)&W[(size_t)(r0 + r) * 1024 + c0 + c];
    tile[r][c + 0] = f2h(v.x);
    tile[r][c + 1] = f2h(v.y);
    tile[r][c + 2] = f2h(v.z);
    tile[r][c + 3] = f2h(v.w);
  }
  __syncthreads();
  const int c = tid >> 2;
  const int rq = (tid & 3) * 16;
  unsigned short outv[16];
#pragma unroll
  for (int j = 0; j < 16; ++j) outv[j] = tile[rq + j][c];
  unsigned short* Tb = WT + (size_t)(c0 + c) * 1024 + r0 + rq;
  ((uint4*)Tb)[0] = ((const uint4*)outv)[0];
  ((uint4*)Tb)[1] = ((const uint4*)outv)[1];
}

// ---------------------------------------------------------------------------
// Row-sum reciprocal, rows of 1024 fp16 (Eq): si[row] = 1/sum(E[row][:])
// ---------------------------------------------------------------------------
__global__ __launch_bounds__(256) void rsum_inv_1k(
    const unsigned short* __restrict__ E, float* __restrict__ si)
{
  const int row = blockIdx.x;
  const int tid = threadIdx.x;
  const uint2 u = ((const uint2*)(E + (size_t)row * 1024))[tid];
  float s = (h2f(u.x & 0xffff) + h2f(u.x >> 16)) +
            (h2f(u.y & 0xffff) + h2f(u.y >> 16));
#pragma unroll
  for (int o = 32; o >= 1; o >>= 1) s += __shfl_xor(s, o);
  __shared__ float rs[4];
  if ((tid & 63) == 0) rs[tid >> 6] = s;
  __syncthreads();
  if (tid == 0) si[row] = 1.f / ((rs[0] + rs[1]) + (rs[2] + rs[3]));
}

// ---------------------------------------------------------------------------
// Row-sum reciprocal, rows of 4096 fp16 (ET): si[row] = 1/sum
// ---------------------------------------------------------------------------
__global__ __launch_bounds__(256) void rsum_inv_4k(
    const unsigned short* __restrict__ ET, float* __restrict__ si)
{
  const int row = blockIdx.x;
  const int tid = threadIdx.x;
  const uint4* p = (const uint4*)(ET + (size_t)row * 4096);
  float s = 0.f;
#pragma unroll
  for (int h = 0; h < 2; ++h) {
    const uint4 u = p[tid * 2 + h];
    s += (h2f(u.x & 0xffff) + h2f(u.x >> 16)) + (h2f(u.y & 0xffff) + h2f(u.y >> 16)) +
         (h2f(u.z & 0xffff) + h2f(u.z >> 16)) + (h2f(u.w & 0xffff) + h2f(u.w >> 16));
  }
#pragma unroll
  for (int o = 32; o >= 1; o >>= 1) s += __shfl_xor(s, o);
  __shared__ float rs[4];
  if ((tid & 63) == 0) rs[tid >> 6] = s;
  __syncthreads();
  if (tid == 0) si[row] = 1.f / ((rs[0] + rs[1]) + (rs[2] + rs[3]));
}

// ---------------------------------------------------------------------------
// split-K x4 reduce of fp16 partials with diag scaling:
// O[b][dk][dv] = f16( (sum_s P[b*4+s][dk][dv]) * sk[b][dk] * sv[b][dv] )
// ---------------------------------------------------------------------------
__global__ __launch_bounds__(256) void red4m(
    const unsigned short* __restrict__ P, const float* __restrict__ sk,
    const float* __restrict__ sv, unsigned short* __restrict__ O)
{
  const int i = blockIdx.x * 256 + threadIdx.x;   // 2^20 groups of 4
  const int b = i >> 18;
  const int j = i & 262143;
  const int dk = j >> 8;
  const int dv0 = (j & 255) << 2;
  float s0 = 0, s1 = 0, s2 = 0, s3 = 0;
#pragma unroll
  for (int sl = 0; sl < 4; ++sl) {
    const uint2 u = *(const uint2*)(P + (((long)(b * 4 + sl)) << 20) + ((long)j << 2));
    s0 += h2f(u.x & 0xffff); s1 += h2f(u.x >> 16);
    s2 += h2f(u.y & 0xffff); s3 += h2f(u.y >> 16);
  }
  const float fk = sk[(b << 10) + dk];
  const float4 fv = *(const float4*)&sv[(b << 10) + dv0];
  unsigned short o4[4] = {f2h(s0 * fk * fv.x), f2h(s1 * fk * fv.y),
                          f2h(s2 * fk * fv.z), f2h(s3 * fk * fv.w)};
  *(uint2*)(O + ((long)b << 20) + ((long)j << 2)) = *(const uint2*)o4;
}

// ---------------------------------------------------------------------------
// split-K x4 reduce, plain: O[b][i] = f16(sum_s P[b*4+s][i])
// ---------------------------------------------------------------------------
__global__ __launch_bounds__(256) void red4h(
    const unsigned short* __restrict__ P, unsigned short* __restrict__ O)
{
  const int i = blockIdx.x * 256 + threadIdx.x;
  const int b = i >> 18;
  const int j = i & 262143;
  float s0 = 0, s1 = 0, s2 = 0, s3 = 0;
#pragma unroll
  for (int sl = 0; sl < 4; ++sl) {
    const uint2 u = *(const uint2*)(P + (((long)(b * 4 + sl)) << 20) + ((long)j << 2));
    s0 += h2f(u.x & 0xffff); s1 += h2f(u.x >> 16);
    s2 += h2f(u.y & 0xffff); s3 += h2f(u.y >> 16);
  }
  unsigned short o4[4] = {f2h(s0), f2h(s1), f2h(s2), f2h(s3)};
  *(uint2*)(O + ((long)b << 20) + ((long)j << 2)) = *(const uint2*)o4;
}

// ---------------------------------------------------------------------------
extern "C" void kernel_launch(void* const* d_in, const int* in_sizes, int n_in,
                              void* d_out, int out_size, void* d_ws, size_t ws_size,
                              hipStream_t stream) {
  const float* q  = (const float*)d_in[0];
  const float* k  = (const float*)d_in[1];
  const float* v  = (const float*)d_in[2];
  const float* Wq = (const float*)d_in[3];
  const float* bq = (const float*)d_in[4];
  const float* Wk = (const float*)d_in[5];
  const float* bk = (const float*)d_in[6];
  const float* Wv = (const float*)d_in[7];
  const float* bv = (const float*)d_in[8];
  const float* Wo = (const float*)d_in[9];
  const float* bo = (const float*)d_in[10];
  float* out = (float*)d_out;

  // workspace layout (~150 MB)
  char* p = (char*)d_ws;
  unsigned short* Xh  = (unsigned short*)p;  p += 33554432;   // fp16 [16384][1024]; later Part (fp16 [16][1024][1024])
  unsigned short* Part = Xh;                                  // alias (Xh dead after V proj)
  unsigned short* WqT = (unsigned short*)p;  p += 2097152;
  unsigned short* WkT = (unsigned short*)p;  p += 2097152;
  unsigned short* WvT = (unsigned short*)p;  p += 2097152;
  unsigned short* WoT = (unsigned short*)p;  p += 2097152;
  unsigned short* Eq  = (unsigned short*)p;  p += 33554432;   // fp16 [4][4096][1024]
  unsigned short* ETk = (unsigned short*)p;  p += 33554432;   // fp16 [4][1024][4096]
  unsigned short* ETv = (unsigned short*)p;  p += 33554432;
  unsigned short* Mh  = (unsigned short*)p;  p += 8388608;    // fp16 [4][1024][1024]
  unsigned short* GTh = (unsigned short*)p;  p += 8388608;    // fp16 [4][1024][1024]
  float* sinvq = (float*)p; p += 16384 * 4;
  float* sk    = (float*)p; p += 4096 * 4;
  float* sv    = (float*)p; p += 4096 * 4;

  const dim3 blk(256);
  const dim3 blk512(512);
  const int N4 = 16777216 / 4;
  const long S22 = 4096L * 1024;   // 2^22
  const long S20 = 1024L * 1024;   // 2^20

  // weights -> fp16 transposed
  w_trh<<<dim3(16, 16), blk, 0, stream>>>(Wq, WqT);
  w_trh<<<dim3(16, 16), blk, 0, stream>>>(Wk, WkT);
  w_trh<<<dim3(16, 16), blk, 0, stream>>>(Wv, WvT);
  w_trh<<<dim3(16, 16), blk, 0, stream>>>(Wo, WoT);

  // ---- Q path: Eq = exp(q@Wq + bq) (normal layout); sinvq = 1/rowsum
  conv_h<<<16384, blk, 0, stream>>>(q, Xh, N4);
  gemmt<3><<<512, blk512, 0, stream>>>(Xh, WqT, Eq, bq, nullptr,
      1024, 1024, 1024, 4, 32, 1, S22, 0, S22);
  rsum_inv_1k<<<16384, blk, 0, stream>>>(Eq, sinvq);

  // ---- K path: ETk[b][d][l] = exp(k@Wk + bk)^T ; sk = 1/colsum
  conv_h<<<16384, blk, 0, stream>>>(k, Xh, N4);
  gemmt<4><<<512, blk512, 0, stream>>>(Xh, WkT, ETk, bk, nullptr,
      1024, 1024, 1024, 4, 32, 1, S22, 0, S22);
  rsum_inv_4k<<<4096, blk, 0, stream>>>(ETk, sk);

  // ---- V path
  conv_h<<<16384, blk, 0, stream>>>(v, Xh, N4);
  gemmt<4><<<512, blk512, 0, stream>>>(Xh, WvT, ETv, bv, nullptr,
      1024, 1024, 1024, 4, 32, 1, S22, 0, S22);
  rsum_inv_4k<<<4096, blk, 0, stream>>>(ETv, sv);

  // ---- Mraw partials: P[b*4+s] = ETk_chunk @ ETv_chunk^T (K=4096 split x4)
  //      Mh = f16(red4(P) * sk[dk] * sv[dv])
  gemmt<2><<<512, blk512, 0, stream>>>(ETk, ETv, Part, nullptr, nullptr,
      1024, 1024, 4096, 4, 8, 4, S22, S22, S20);
  red4m<<<4096, blk, 0, stream>>>(Part, sk, sv, Mh);

  // ---- GT_b = (M_b @ Wo)^T = WoT @ M_b^T : K=1024 split x4
  gemmt<2><<<512, blk512, 0, stream>>>(WoT, Mh, Part, nullptr, nullptr,
      1024, 256, 1024, 4, 8, 4, 0, S20, S20);
  red4h<<<4096, blk, 0, stream>>>(Part, GTh);

  // ---- Out_b = diag(sinvq) * (Eq_b @ GT_b^T) + bo
  gemmt<5><<<512, blk512, 0, stream>>>(Eq, GTh, out, bo, sinvq,
      1024, 1024, 1024, 4, 32, 1, S22, S20, S22);

  (void)in_sizes; (void)n_in; (void)out_size; (void)ws_size;
}

// Round 10
// 320.417 us; speedup vs baseline: 1.5594x; 1.0156x over previous
//
#include <hip/hip_runtime.h>

typedef _Float16 f16x8 __attribute__((ext_vector_type(8)));
typedef float f32x4 __attribute__((ext_vector_type(4)));

__device__ __forceinline__ float h2f(unsigned short h) {
  return (float)__builtin_bit_cast(_Float16, h);
}
__device__ __forceinline__ unsigned short f2h(float f) {
  return __builtin_bit_cast(unsigned short, (_Float16)f);
}

__device__ __forceinline__ void gload_lds16(const void* g, void* l) {
  __builtin_amdgcn_global_load_lds(
      (const __attribute__((address_space(1))) void*)g,
      (__attribute__((address_space(3))) void*)l, 16, 0, 0);
}

// ---------------------------------------------------------------------------
// 128x256 tile GEMM, C = A @ Bt^T (fp16 MFMA, fp32 acc) — round-7/9 proven
// core: single 48KB LDS buffer, 8 waves (2M x 4N), plain syncthreads loop,
// XOR-swizzled LDS (conflict-free ds_read_b128), XCD-swizzled 1D grid.
// ASRC 0: A fp16, global_load_lds staging.
// ASRC 1: A fp32, reg-staged (2x float4 at inverse-swizzled fp32 addr -> RNE
//         cvt -> ds_write_b128 to the same linear LDS slot) — fuses the
//         fp32->fp16 conversion pass. Writes are after the loop-closing
//         barrier => no race with prior reads.
// OUTMODE 0: fp32 + bias[col]
//         2: fp16 split-K partial (slice zt), no bias
//         3: fp16 exp(acc + bias[col]), normal [row][col] layout (Q path)
//         4: fp16 exp(acc + bias[col]), TRANSPOSED: ET[col][row], packed 8B
//         5: fp32 acc*sinv[row] + bias[col]  (fused row-softmax + out)
// ---------------------------------------------------------------------------
template <int ASRC, int OUTMODE>
__global__ __launch_bounds__(512, 4) void gemmt(
    const void* __restrict__ Av, const unsigned short* __restrict__ Bt,
    void* __restrict__ Cv, const float* __restrict__ bias,
    const float* __restrict__ sinv,
    int N, int K, int ldk, int gx, int gy, int nsplit,
    long sA, long sB, long sC)
{
  __shared__ alignas(16) unsigned char smem[49152];  // A 16KB | B 32KB
  const int tid  = threadIdx.x;
  const int lane = tid & 63;
  const int wave = tid >> 6;
  const int waveM = wave >> 2;      // 0..1 (64 rows each)
  const int waveN = wave & 3;       // 0..3 (64 cols each)

  // bijective XCD swizzle (nwg % 8 == 0 for all launches here)
  const int nwg = (int)gridDim.x;
  const int cpx = nwg >> 3;
  const int wg  = (int)blockIdx.x;
  const int w   = (wg & 7) * cpx + (wg >> 3);
  const int x   = w % gx;
  const int rem = w / gx;
  const int y   = rem % gy;
  const int zt  = rem / gy;
  const int bz  = zt / nsplit;
  const int sp  = zt % nsplit;

  const int m0 = y * 128, n0 = x * 256;
  const size_t ldkB = (size_t)ldk * 2;
  const size_t ldkB64 = ldkB * 64, ldkB128 = ldkB * 128;

  // staging addresses (dst linear tid*16 (+8192); src inverse-swizzled)
  const int srow = tid >> 3;                         // 0..63
  const int scol = ((tid * 16) & 127) ^ ((srow & 7) << 4);   // fp16-bytes
  const char* ApR16 = nullptr;   // ASRC==0
  const char* ApR32 = nullptr;   // ASRC==1
  const char* BpR;
  {
    const char* Bb = (const char*)(Bt + (long)bz * sB + (long)sp * K) + (size_t)n0 * ldkB;
    BpR = Bb + (size_t)srow * ldkB + scol;
    if (ASRC == 0) {
      const char* Ab = (const char*)Av + ((long)bz * sA + (long)sp * K) * 2
                       + (size_t)m0 * ldkB;
      ApR16 = Ab + (size_t)srow * ldkB + scol;
    } else {
      const char* Ab = (const char*)Av + ((long)bz * sA + (long)sp * K) * 4
                       + (size_t)m0 * (size_t)ldk * 4;
      ApR32 = Ab + (size_t)srow * (size_t)ldk * 4 + (size_t)scol * 2;
    }
  }
  const unsigned oA0 = (unsigned)tid * 16;
  const size_t ldk32_64 = (size_t)ldk * 4 * 64;      // 64 rows of fp32

  // ds_read byte offsets (kk=0); kk=1 offset = kk0 ^ 64 (bits 4-6 swizzle field)
  int offA[4], offB[4];
  {
    const int q16 = (lane >> 4) << 4;
#pragma unroll
    for (int mi = 0; mi < 4; ++mi) {
      const int r = waveM * 64 + mi * 16 + (lane & 15);
      offA[mi] = r * 128 + (q16 ^ ((r & 7) << 4));
    }
#pragma unroll
    for (int ni = 0; ni < 4; ++ni) {
      const int r = waveN * 64 + ni * 16 + (lane & 15);
      offB[ni] = 16384 + r * 128 + (q16 ^ ((r & 7) << 4));
    }
  }

  f32x4 acc[4][4] = {};

  const int nk = K >> 6;
  for (int kt = 0; kt < nk; ++kt) {
    const size_t kb = (size_t)kt * 128;              // fp16 bytes per K-tile
    if (ASRC == 0) {
      gload_lds16(ApR16 + kb,           smem + oA0);
      gload_lds16(ApR16 + ldkB64 + kb,  smem + oA0 + 8192);
    } else {
      const char* s0 = ApR32 + (size_t)kt * 256;     // fp32 bytes per K-tile
      const char* s1 = s0 + ldk32_64;
      const float4 a0 = *(const float4*)s0;
      const float4 a1 = *(const float4*)(s0 + 16);
      const float4 b0 = *(const float4*)s1;
      const float4 b1 = *(const float4*)(s1 + 16);
      unsigned short h0[8], h1[8];
      const float* fa0 = (const float*)&a0; const float* fa1 = (const float*)&a1;
      const float* fb0 = (const float*)&b0; const float* fb1 = (const float*)&b1;
#pragma unroll
      for (int e = 0; e < 4; ++e) {
        h0[e] = f2h(fa0[e]); h0[4 + e] = f2h(fa1[e]);
        h1[e] = f2h(fb0[e]); h1[4 + e] = f2h(fb1[e]);
      }
      *(uint4*)&smem[oA0]        = *(const uint4*)h0;
      *(uint4*)&smem[oA0 + 8192] = *(const uint4*)h1;
    }
    gload_lds16(BpR + kb,                     smem + 16384 + oA0);
    gload_lds16(BpR + ldkB64 + kb,            smem + 16384 + oA0 + 8192);
    gload_lds16(BpR + ldkB128 + kb,           smem + 16384 + oA0 + 16384);
    gload_lds16(BpR + ldkB128 + ldkB64 + kb,  smem + 16384 + oA0 + 24576);
    __syncthreads();
#pragma unroll
    for (int kk = 0; kk < 2; ++kk) {
      const int kx = kk << 6;
      f16x8 aF[4], bF[4];
#pragma unroll
      for (int mi = 0; mi < 4; ++mi) aF[mi] = *(const f16x8*)&smem[offA[mi] ^ kx];
#pragma unroll
      for (int ni = 0; ni < 4; ++ni) bF[ni] = *(const f16x8*)&smem[offB[ni] ^ kx];
#pragma unroll
      for (int mi = 0; mi < 4; ++mi)
#pragma unroll
        for (int ni = 0; ni < 4; ++ni)
          acc[mi][ni] = __builtin_amdgcn_mfma_f32_16x16x32_f16(aF[mi], bF[ni], acc[mi][ni], 0, 0, 0);
    }
    __syncthreads();
  }

  // epilogue
  const int rb = (lane >> 4) * 4;
  const int cb_ = lane & 15;
  const long zout = (OUTMODE == 2) ? (long)zt : (long)bz;
#pragma unroll
  for (int m = 0; m < 4; ++m) {
#pragma unroll
    for (int n = 0; n < 4; ++n) {
      const int col = n0 + waveN * 64 + n * 16 + cb_;
      const int row0 = m0 + waveM * 64 + m * 16 + rb;
      if (OUTMODE == 4) {
        const float badd = bias[col];
        unsigned short o4[4];
#pragma unroll
        for (int r = 0; r < 4; ++r) o4[r] = f2h(__expf(acc[m][n][r] + badd));
        *(uint2*)((unsigned short*)Cv + zout * sC + ((size_t)col << 12) + row0) =
            *(const uint2*)o4;
      } else if (OUTMODE == 3) {
        const float badd = bias[col];
#pragma unroll
        for (int r = 0; r < 4; ++r)
          ((unsigned short*)Cv)[zout * sC + (size_t)(row0 + r) * N + col] =
              f2h(__expf(acc[m][n][r] + badd));
      } else if (OUTMODE == 2) {
#pragma unroll
        for (int r = 0; r < 4; ++r)
          ((unsigned short*)Cv)[zout * sC + (size_t)(row0 + r) * N + col] = f2h(acc[m][n][r]);
      } else if (OUTMODE == 5) {
        const float badd = bias[col];
        const float4 sv4 = *(const float4*)&sinv[zout * 4096 + row0];
        const float* svp = (const float*)&sv4;
#pragma unroll
        for (int r = 0; r < 4; ++r)
          ((float*)Cv)[zout * sC + (size_t)(row0 + r) * N + col] = acc[m][n][r] * svp[r] + badd;
      } else {
        const float badd = bias[col];
#pragma unroll
        for (int r = 0; r < 4; ++r)
          ((float*)Cv)[zout * sC + (size_t)(row0 + r) * N + col] = acc[m][n][r] + badd;
      }
    }
  }
}

// ---------------------------------------------------------------------------
// Weight transpose + fp16: WT[c][r] = f16(W[r][c]), 1024x1024
// ---------------------------------------------------------------------------
__global__ __launch_bounds__(256) void w_trh(
    const float* __restrict__ W, unsigned short* __restrict__ WT)
{
  __shared__ unsigned short tile[64][73];
  const int c0 = blockIdx.x * 64;
  const int r0 = blockIdx.y * 64;
  const int tid = threadIdx.x;
  const int r = tid >> 2;
  const int cq = (tid & 3) * 16;
#pragma unroll
  for (int i = 0; i < 4; ++i) {
    const int c = cq + i * 4;
    const float4 v = *(const float4*)&W[(size_t)(r0 + r) * 1024 + c0 + c];
    tile[r][c + 0] = f2h(v.x);
    tile[r][c + 1] = f2h(v.y);
    tile[r][c + 2] = f2h(v.z);
    tile[r][c + 3] = f2h(v.w);
  }
  __syncthreads();
  const int c = tid >> 2;
  const int rq = (tid & 3) * 16;
  unsigned short outv[16];
#pragma unroll
  for (int j = 0; j < 16; ++j) outv[j] = tile[rq + j][c];
  unsigned short* Tb = WT + (size_t)(c0 + c) * 1024 + r0 + rq;
  ((uint4*)Tb)[0] = ((const uint4*)outv)[0];
  ((uint4*)Tb)[1] = ((const uint4*)outv)[1];
}

// ---------------------------------------------------------------------------
// Row-sum reciprocal, rows of 1024 fp16 (Eq): si[row] = 1/sum(E[row][:])
// ---------------------------------------------------------------------------
__global__ __launch_bounds__(256) void rsum_inv_1k(
    const unsigned short* __restrict__ E, float* __restrict__ si)
{
  const int row = blockIdx.x;
  const int tid = threadIdx.x;
  const uint2 u = ((const uint2*)(E + (size_t)row * 1024))[tid];
  float s = (h2f(u.x & 0xffff) + h2f(u.x >> 16)) +
            (h2f(u.y & 0xffff) + h2f(u.y >> 16));
#pragma unroll
  for (int o = 32; o >= 1; o >>= 1) s += __shfl_xor(s, o);
  __shared__ float rs[4];
  if ((tid & 63) == 0) rs[tid >> 6] = s;
  __syncthreads();
  if (tid == 0) si[row] = 1.f / ((rs[0] + rs[1]) + (rs[2] + rs[3]));
}

// ---------------------------------------------------------------------------
// Row-sum reciprocal, rows of 4096 fp16 (ET): si[row] = 1/sum
// ---------------------------------------------------------------------------
__global__ __launch_bounds__(256) void rsum_inv_4k(
    const unsigned short* __restrict__ ET, float* __restrict__ si)
{
  const int row = blockIdx.x;
  const int tid = threadIdx.x;
  const uint4* p = (const uint4*)(ET + (size_t)row * 4096);
  float s = 0.f;
#pragma unroll
  for (int h = 0; h < 2; ++h) {
    const uint4 u = p[tid * 2 + h];
    s += (h2f(u.x & 0xffff) + h2f(u.x >> 16)) + (h2f(u.y & 0xffff) + h2f(u.y >> 16)) +
         (h2f(u.z & 0xffff) + h2f(u.z >> 16)) + (h2f(u.w & 0xffff) + h2f(u.w >> 16));
  }
#pragma unroll
  for (int o = 32; o >= 1; o >>= 1) s += __shfl_xor(s, o);
  __shared__ float rs[4];
  if ((tid & 63) == 0) rs[tid >> 6] = s;
  __syncthreads();
  if (tid == 0) si[row] = 1.f / ((rs[0] + rs[1]) + (rs[2] + rs[3]));
}

// ---------------------------------------------------------------------------
// split-K x4 reduce of fp16 partials with diag scaling:
// O[b][dk][dv] = f16( (sum_s P[b*4+s][dk][dv]) * sk[b][dk] * sv[b][dv] )
// ---------------------------------------------------------------------------
__global__ __launch_bounds__(256) void red4m(
    const unsigned short* __restrict__ P, const float* __restrict__ sk,
    const float* __restrict__ sv, unsigned short* __restrict__ O)
{
  const int i = blockIdx.x * 256 + threadIdx.x;   // 2^20 groups of 4
  const int b = i >> 18;
  const int j = i & 262143;
  const int dk = j >> 8;
  const int dv0 = (j & 255) << 2;
  float s0 = 0, s1 = 0, s2 = 0, s3 = 0;
#pragma unroll
  for (int sl = 0; sl < 4; ++sl) {
    const uint2 u = *(const uint2*)(P + (((long)(b * 4 + sl)) << 20) + ((long)j << 2));
    s0 += h2f(u.x & 0xffff); s1 += h2f(u.x >> 16);
    s2 += h2f(u.y & 0xffff); s3 += h2f(u.y >> 16);
  }
  const float fk = sk[(b << 10) + dk];
  const float4 fv = *(const float4*)&sv[(b << 10) + dv0];
  unsigned short o4[4] = {f2h(s0 * fk * fv.x), f2h(s1 * fk * fv.y),
                          f2h(s2 * fk * fv.z), f2h(s3 * fk * fv.w)};
  *(uint2*)(O + ((long)b << 20) + ((long)j << 2)) = *(const uint2*)o4;
}

// ---------------------------------------------------------------------------
// split-K x4 reduce, plain: O[b][i] = f16(sum_s P[b*4+s][i])
// ---------------------------------------------------------------------------
__global__ __launch_bounds__(256) void red4h(
    const unsigned short* __restrict__ P, unsigned short* __restrict__ O)
{
  const int i = blockIdx.x * 256 + threadIdx.x;
  const int b = i >> 18;
  const int j = i & 262143;
  float s0 = 0, s1 = 0, s2 = 0, s3 = 0;
#pragma unroll
  for (int sl = 0; sl < 4; ++sl) {
    const uint2 u = *(const uint2*)(P + (((long)(b * 4 + sl)) << 20) + ((long)j << 2));
    s0 += h2f(u.x & 0xffff); s1 += h2f(u.x >> 16);
    s2 += h2f(u.y & 0xffff); s3 += h2f(u.y >> 16);
  }
  unsigned short o4[4] = {f2h(s0), f2h(s1), f2h(s2), f2h(s3)};
  *(uint2*)(O + ((long)b << 20) + ((long)j << 2)) = *(const uint2*)o4;
}

// ---------------------------------------------------------------------------
extern "C" void kernel_launch(void* const* d_in, const int* in_sizes, int n_in,
                              void* d_out, int out_size, void* d_ws, size_t ws_size,
                              hipStream_t stream) {
  const float* q  = (const float*)d_in[0];
  const float* k  = (const float*)d_in[1];
  const float* v  = (const float*)d_in[2];
  const float* Wq = (const float*)d_in[3];
  const float* bq = (const float*)d_in[4];
  const float* Wk = (const float*)d_in[5];
  const float* bk = (const float*)d_in[6];
  const float* Wv = (const float*)d_in[7];
  const float* bv = (const float*)d_in[8];
  const float* Wo = (const float*)d_in[9];
  const float* bo = (const float*)d_in[10];
  float* out = (float*)d_out;

  // workspace layout (~150 MB)
  char* p = (char*)d_ws;
  unsigned short* Part = (unsigned short*)p; p += 33554432;   // fp16 [16][1024][1024]
  unsigned short* WqT = (unsigned short*)p;  p += 2097152;
  unsigned short* WkT = (unsigned short*)p;  p += 2097152;
  unsigned short* WvT = (unsigned short*)p;  p += 2097152;
  unsigned short* WoT = (unsigned short*)p;  p += 2097152;
  unsigned short* Eq  = (unsigned short*)p;  p += 33554432;   // fp16 [4][4096][1024]
  unsigned short* ETk = (unsigned short*)p;  p += 33554432;   // fp16 [4][1024][4096]
  unsigned short* ETv = (unsigned short*)p;  p += 33554432;
  unsigned short* Mh  = (unsigned short*)p;  p += 8388608;    // fp16 [4][1024][1024]
  unsigned short* GTh = (unsigned short*)p;  p += 8388608;    // fp16 [4][1024][1024]
  float* sinvq = (float*)p; p += 16384 * 4;
  float* sk    = (float*)p; p += 4096 * 4;
  float* sv    = (float*)p; p += 4096 * 4;

  const dim3 blk(256);
  const dim3 blk512(512);
  const long S22 = 4096L * 1024;   // 2^22
  const long S20 = 1024L * 1024;   // 2^20

  // weights -> fp16 transposed
  w_trh<<<dim3(16, 16), blk, 0, stream>>>(Wq, WqT);
  w_trh<<<dim3(16, 16), blk, 0, stream>>>(Wk, WkT);
  w_trh<<<dim3(16, 16), blk, 0, stream>>>(Wv, WvT);
  w_trh<<<dim3(16, 16), blk, 0, stream>>>(Wo, WoT);

  // ---- Q path: Eq = exp(q@Wq + bq) (fp32 A, fused cvt); sinvq = 1/rowsum
  gemmt<1, 3><<<512, blk512, 0, stream>>>(q, WqT, Eq, bq, nullptr,
      1024, 1024, 1024, 4, 32, 1, S22, 0, S22);
  rsum_inv_1k<<<16384, blk, 0, stream>>>(Eq, sinvq);

  // ---- K path: ETk[b][d][l] = exp(k@Wk + bk)^T ; sk = 1/colsum
  gemmt<1, 4><<<512, blk512, 0, stream>>>(k, WkT, ETk, bk, nullptr,
      1024, 1024, 1024, 4, 32, 1, S22, 0, S22);
  rsum_inv_4k<<<4096, blk, 0, stream>>>(ETk, sk);

  // ---- V path
  gemmt<1, 4><<<512, blk512, 0, stream>>>(v, WvT, ETv, bv, nullptr,
      1024, 1024, 1024, 4, 32, 1, S22, 0, S22);
  rsum_inv_4k<<<4096, blk, 0, stream>>>(ETv, sv);

  // ---- Mraw partials: P[b*4+s] = ETk_chunk @ ETv_chunk^T (K=4096 split x4)
  //      Mh = f16(red4(P) * sk[dk] * sv[dv])
  gemmt<0, 2><<<512, blk512, 0, stream>>>(ETk, ETv, Part, nullptr, nullptr,
      1024, 1024, 4096, 4, 8, 4, S22, S22, S20);
  red4m<<<4096, blk, 0, stream>>>(Part, sk, sv, Mh);

  // ---- GT_b = (M_b @ Wo)^T = WoT @ M_b^T : K=1024 split x4
  gemmt<0, 2><<<512, blk512, 0, stream>>>(WoT, Mh, Part, nullptr, nullptr,
      1024, 256, 1024, 4, 8, 4, 0, S20, S20);
  red4h<<<4096, blk, 0, stream>>>(Part, GTh);

  // ---- Out_b = diag(sinvq) * (Eq_b @ GT_b^T) + bo
  gemmt<0, 5><<<512, blk512, 0, stream>>>(Eq, GTh, out, bo, sinvq,
      1024, 1024, 1024, 4, 32, 1, S22, S20, S22);

  (void)in_sizes; (void)n_in; (void)out_size; (void)ws_size;
}

// Round 11
// 314.153 us; speedup vs baseline: 1.5905x; 1.0199x over previous
//
#include <hip/hip_runtime.h>

typedef _Float16 f16x8 __attribute__((ext_vector_type(8)));
typedef float f32x4 __attribute__((ext_vector_type(4)));

__device__ __forceinline__ float h2f(unsigned short h) {
  return (float)__builtin_bit_cast(_Float16, h);
}
__device__ __forceinline__ unsigned short f2h(float f) {
  return __builtin_bit_cast(unsigned short, (_Float16)f);
}

__device__ __forceinline__ void gload_lds16(const void* g, void* l) {
  __builtin_amdgcn_global_load_lds(
      (const __attribute__((address_space(1))) void*)g,
      (__attribute__((address_space(3))) void*)l, 16, 0, 0);
}

// ---------------------------------------------------------------------------
// 128x256 tile GEMM, C = A @ Bt^T (fp16 MFMA, fp32 acc) — round-7/9 proven
// core: single 48KB LDS buffer, 8 waves (2M x 4N), plain syncthreads loop,
// XOR-swizzled LDS (conflict-free ds_read_b128), XCD-swizzled 1D grid.
// ASRC 0: A fp16, global_load_lds staging.
// ASRC 1: A fp32, T14 issue-early/write-late: tile kt+1's fp32 loads issue
//         during iter kt (drained by the barrier together with B's gloads —
//         one exposed HBM round, not two serial); cvt+ds_write at iter top
//         run from registers (prior closing barrier => buffer has no readers).
// OUTMODE 0: fp32 + bias[col]
//         2: fp16 split-K partial (slice zt), no bias
//         3: fp16 exp(acc + bias[col]), normal [row][col] layout (Q path)
//         4: fp16 exp(acc + bias[col]), TRANSPOSED: ET[col][row], packed 8B
//         5: fp32 acc*sinv[row] + bias[col]  (fused row-softmax + out)
// ---------------------------------------------------------------------------
template <int ASRC, int OUTMODE>
__global__ __launch_bounds__(512, 4) void gemmt(
    const void* __restrict__ Av, const unsigned short* __restrict__ Bt,
    void* __restrict__ Cv, const float* __restrict__ bias,
    const float* __restrict__ sinv,
    int N, int K, int ldk, int gx, int gy, int nsplit,
    long sA, long sB, long sC)
{
  __shared__ alignas(16) unsigned char smem[49152];  // A 16KB | B 32KB
  const int tid  = threadIdx.x;
  const int lane = tid & 63;
  const int wave = tid >> 6;
  const int waveM = wave >> 2;      // 0..1 (64 rows each)
  const int waveN = wave & 3;       // 0..3 (64 cols each)

  // bijective XCD swizzle (nwg % 8 == 0 for all launches here)
  const int nwg = (int)gridDim.x;
  const int cpx = nwg >> 3;
  const int wg  = (int)blockIdx.x;
  const int w   = (wg & 7) * cpx + (wg >> 3);
  const int x   = w % gx;
  const int rem = w / gx;
  const int y   = rem % gy;
  const int zt  = rem / gy;
  const int bz  = zt / nsplit;
  const int sp  = zt % nsplit;

  const int m0 = y * 128, n0 = x * 256;
  const size_t ldkB = (size_t)ldk * 2;
  const size_t ldkB64 = ldkB * 64, ldkB128 = ldkB * 128;

  // staging addresses (dst linear tid*16 (+8192); src inverse-swizzled)
  const int srow = tid >> 3;                         // 0..63
  const int scol = ((tid * 16) & 127) ^ ((srow & 7) << 4);   // fp16-bytes
  const char* ApR16 = nullptr;   // ASRC==0
  const char* ApR32 = nullptr;   // ASRC==1
  const char* BpR;
  {
    const char* Bb = (const char*)(Bt + (long)bz * sB + (long)sp * K) + (size_t)n0 * ldkB;
    BpR = Bb + (size_t)srow * ldkB + scol;
    if (ASRC == 0) {
      const char* Ab = (const char*)Av + ((long)bz * sA + (long)sp * K) * 2
                       + (size_t)m0 * ldkB;
      ApR16 = Ab + (size_t)srow * ldkB + scol;
    } else {
      const char* Ab = (const char*)Av + ((long)bz * sA + (long)sp * K) * 4
                       + (size_t)m0 * (size_t)ldk * 4;
      ApR32 = Ab + (size_t)srow * (size_t)ldk * 4 + (size_t)scol * 2;
    }
  }
  const unsigned oA0 = (unsigned)tid * 16;
  const size_t ldk32_64 = (size_t)ldk * 4 * 64;      // 64 rows of fp32

  // ds_read byte offsets (kk=0); kk=1 offset = kk0 ^ 64 (bits 4-6 swizzle field)
  int offA[4], offB[4];
  {
    const int q16 = (lane >> 4) << 4;
#pragma unroll
    for (int mi = 0; mi < 4; ++mi) {
      const int r = waveM * 64 + mi * 16 + (lane & 15);
      offA[mi] = r * 128 + (q16 ^ ((r & 7) << 4));
    }
#pragma unroll
    for (int ni = 0; ni < 4; ++ni) {
      const int r = waveN * 64 + ni * 16 + (lane & 15);
      offB[ni] = 16384 + r * 128 + (q16 ^ ((r & 7) << 4));
    }
  }

  f32x4 acc[4][4] = {};

  // T14 prefetch registers (ASRC==1): tile-kt fp32 A values live here at the
  // top of iteration kt.
  float4 pf0, pf1, pf2, pf3;
  if (ASRC == 1) {
    const char* s0 = ApR32;
    const char* s1 = s0 + ldk32_64;
    pf0 = *(const float4*)s0;  pf1 = *(const float4*)(s0 + 16);
    pf2 = *(const float4*)s1;  pf3 = *(const float4*)(s1 + 16);
  }

  const int nk = K >> 6;
  for (int kt = 0; kt < nk; ++kt) {
    const size_t kb = (size_t)kt * 128;              // fp16 bytes per K-tile
    if (ASRC == 0) {
      gload_lds16(ApR16 + kb,           smem + oA0);
      gload_lds16(ApR16 + ldkB64 + kb,  smem + oA0 + 8192);
    } else {
      // write phase: cvt tile-kt regs -> LDS (no load wait; buffer reader-free)
      unsigned short h0[8], h1[8];
      const float* fa0 = (const float*)&pf0; const float* fa1 = (const float*)&pf1;
      const float* fb0 = (const float*)&pf2; const float* fb1 = (const float*)&pf3;
#pragma unroll
      for (int e = 0; e < 4; ++e) {
        h0[e] = f2h(fa0[e]); h0[4 + e] = f2h(fa1[e]);
        h1[e] = f2h(fb0[e]); h1[4 + e] = f2h(fb1[e]);
      }
      *(uint4*)&smem[oA0]        = *(const uint4*)h0;
      *(uint4*)&smem[oA0 + 8192] = *(const uint4*)h1;
      // issue phase: tile kt+1 fp32 loads (drained by the upcoming barrier,
      // overlapped with B's gload_lds below)
      if (kt + 1 < nk) {
        const char* s0 = ApR32 + (size_t)(kt + 1) * 256;
        const char* s1 = s0 + ldk32_64;
        pf0 = *(const float4*)s0;  pf1 = *(const float4*)(s0 + 16);
        pf2 = *(const float4*)s1;  pf3 = *(const float4*)(s1 + 16);
      }
    }
    gload_lds16(BpR + kb,                     smem + 16384 + oA0);
    gload_lds16(BpR + ldkB64 + kb,            smem + 16384 + oA0 + 8192);
    gload_lds16(BpR + ldkB128 + kb,           smem + 16384 + oA0 + 16384);
    gload_lds16(BpR + ldkB128 + ldkB64 + kb,  smem + 16384 + oA0 + 24576);
    __syncthreads();
#pragma unroll
    for (int kk = 0; kk < 2; ++kk) {
      const int kx = kk << 6;
      f16x8 aF[4], bF[4];
#pragma unroll
      for (int mi = 0; mi < 4; ++mi) aF[mi] = *(const f16x8*)&smem[offA[mi] ^ kx];
#pragma unroll
      for (int ni = 0; ni < 4; ++ni) bF[ni] = *(const f16x8*)&smem[offB[ni] ^ kx];
#pragma unroll
      for (int mi = 0; mi < 4; ++mi)
#pragma unroll
        for (int ni = 0; ni < 4; ++ni)
          acc[mi][ni] = __builtin_amdgcn_mfma_f32_16x16x32_f16(aF[mi], bF[ni], acc[mi][ni], 0, 0, 0);
    }
    __syncthreads();
  }

  // epilogue
  const int rb = (lane >> 4) * 4;
  const int cb_ = lane & 15;
  const long zout = (OUTMODE == 2) ? (long)zt : (long)bz;
#pragma unroll
  for (int m = 0; m < 4; ++m) {
#pragma unroll
    for (int n = 0; n < 4; ++n) {
      const int col = n0 + waveN * 64 + n * 16 + cb_;
      const int row0 = m0 + waveM * 64 + m * 16 + rb;
      if (OUTMODE == 4) {
        const float badd = bias[col];
        unsigned short o4[4];
#pragma unroll
        for (int r = 0; r < 4; ++r) o4[r] = f2h(__expf(acc[m][n][r] + badd));
        *(uint2*)((unsigned short*)Cv + zout * sC + ((size_t)col << 12) + row0) =
            *(const uint2*)o4;
      } else if (OUTMODE == 3) {
        const float badd = bias[col];
#pragma unroll
        for (int r = 0; r < 4; ++r)
          ((unsigned short*)Cv)[zout * sC + (size_t)(row0 + r) * N + col] =
              f2h(__expf(acc[m][n][r] + badd));
      } else if (OUTMODE == 2) {
#pragma unroll
        for (int r = 0; r < 4; ++r)
          ((unsigned short*)Cv)[zout * sC + (size_t)(row0 + r) * N + col] = f2h(acc[m][n][r]);
      } else if (OUTMODE == 5) {
        const float badd = bias[col];
        const float4 sv4 = *(const float4*)&sinv[zout * 4096 + row0];
        const float* svp = (const float*)&sv4;
#pragma unroll
        for (int r = 0; r < 4; ++r)
          ((float*)Cv)[zout * sC + (size_t)(row0 + r) * N + col] = acc[m][n][r] * svp[r] + badd;
      } else {
        const float badd = bias[col];
#pragma unroll
        for (int r = 0; r < 4; ++r)
          ((float*)Cv)[zout * sC + (size_t)(row0 + r) * N + col] = acc[m][n][r] + badd;
      }
    }
  }
}

// ---------------------------------------------------------------------------
// Weight transpose + fp16: WT[c][r] = f16(W[r][c]), 1024x1024
// ---------------------------------------------------------------------------
__global__ __launch_bounds__(256) void w_trh(
    const float* __restrict__ W, unsigned short* __restrict__ WT)
{
  __shared__ unsigned short tile[64][73];
  const int c0 = blockIdx.x * 64;
  const int r0 = blockIdx.y * 64;
  const int tid = threadIdx.x;
  const int r = tid >> 2;
  const int cq = (tid & 3) * 16;
#pragma unroll
  for (int i = 0; i < 4; ++i) {
    const int c = cq + i * 4;
    const float4 v = *(const float4*)&W[(size_t)(r0 + r) * 1024 + c0 + c];
    tile[r][c + 0] = f2h(v.x);
    tile[r][c + 1] = f2h(v.y);
    tile[r][c + 2] = f2h(v.z);
    tile[r][c + 3] = f2h(v.w);
  }
  __syncthreads();
  const int c = tid >> 2;
  const int rq = (tid & 3) * 16;
  unsigned short outv[16];
#pragma unroll
  for (int j = 0; j < 16; ++j) outv[j] = tile[rq + j][c];
  unsigned short* Tb = WT + (size_t)(c0 + c) * 1024 + r0 + rq;
  ((uint4*)Tb)[0] = ((const uint4*)outv)[0];
  ((uint4*)Tb)[1] = ((const uint4*)outv)[1];
}

// ---------------------------------------------------------------------------
// Row-sum reciprocal, rows of 1024 fp16 (Eq): si[row] = 1/sum(E[row][:])
// ---------------------------------------------------------------------------
__global__ __launch_bounds__(256) void rsum_inv_1k(
    const unsigned short* __restrict__ E, float* __restrict__ si)
{
  const int row = blockIdx.x;
  const int tid = threadIdx.x;
  const uint2 u = ((const uint2*)(E + (size_t)row * 1024))[tid];
  float s = (h2f(u.x & 0xffff) + h2f(u.x >> 16)) +
            (h2f(u.y & 0xffff) + h2f(u.y >> 16));
#pragma unroll
  for (int o = 32; o >= 1; o >>= 1) s += __shfl_xor(s, o);
  __shared__ float rs[4];
  if ((tid & 63) == 0) rs[tid >> 6] = s;
  __syncthreads();
  if (tid == 0) si[row] = 1.f / ((rs[0] + rs[1]) + (rs[2] + rs[3]));
}

// ---------------------------------------------------------------------------
// Row-sum reciprocal, rows of 4096 fp16 (ET): si[row] = 1/sum
// ---------------------------------------------------------------------------
__global__ __launch_bounds__(256) void rsum_inv_4k(
    const unsigned short* __restrict__ ET, float* __restrict__ si)
{
  const int row = blockIdx.x;
  const int tid = threadIdx.x;
  const uint4* p = (const uint4*)(ET + (size_t)row * 4096);
  float s = 0.f;
#pragma unroll
  for (int h = 0; h < 2; ++h) {
    const uint4 u = p[tid * 2 + h];
    s += (h2f(u.x & 0xffff) + h2f(u.x >> 16)) + (h2f(u.y & 0xffff) + h2f(u.y >> 16)) +
         (h2f(u.z & 0xffff) + h2f(u.z >> 16)) + (h2f(u.w & 0xffff) + h2f(u.w >> 16));
  }
#pragma unroll
  for (int o = 32; o >= 1; o >>= 1) s += __shfl_xor(s, o);
  __shared__ float rs[4];
  if ((tid & 63) == 0) rs[tid >> 6] = s;
  __syncthreads();
  if (tid == 0) si[row] = 1.f / ((rs[0] + rs[1]) + (rs[2] + rs[3]));
}

// ---------------------------------------------------------------------------
// split-K x4 reduce of fp16 partials with diag scaling:
// O[b][dk][dv] = f16( (sum_s P[b*4+s][dk][dv]) * sk[b][dk] * sv[b][dv] )
// ---------------------------------------------------------------------------
__global__ __launch_bounds__(256) void red4m(
    const unsigned short* __restrict__ P, const float* __restrict__ sk,
    const float* __restrict__ sv, unsigned short* __restrict__ O)
{
  const int i = blockIdx.x * 256 + threadIdx.x;   // 2^20 groups of 4
  const int b = i >> 18;
  const int j = i & 262143;
  const int dk = j >> 8;
  const int dv0 = (j & 255) << 2;
  float s0 = 0, s1 = 0, s2 = 0, s3 = 0;
#pragma unroll
  for (int sl = 0; sl < 4; ++sl) {
    const uint2 u = *(const uint2*)(P + (((long)(b * 4 + sl)) << 20) + ((long)j << 2));
    s0 += h2f(u.x & 0xffff); s1 += h2f(u.x >> 16);
    s2 += h2f(u.y & 0xffff); s3 += h2f(u.y >> 16);
  }
  const float fk = sk[(b << 10) + dk];
  const float4 fv = *(const float4*)&sv[(b << 10) + dv0];
  unsigned short o4[4] = {f2h(s0 * fk * fv.x), f2h(s1 * fk * fv.y),
                          f2h(s2 * fk * fv.z), f2h(s3 * fk * fv.w)};
  *(uint2*)(O + ((long)b << 20) + ((long)j << 2)) = *(const uint2*)o4;
}

// ---------------------------------------------------------------------------
// split-K x4 reduce, plain: O[b][i] = f16(sum_s P[b*4+s][i])
// ---------------------------------------------------------------------------
__global__ __launch_bounds__(256) void red4h(
    const unsigned short* __restrict__ P, unsigned short* __restrict__ O)
{
  const int i = blockIdx.x * 256 + threadIdx.x;
  const int b = i >> 18;
  const int j = i & 262143;
  float s0 = 0, s1 = 0, s2 = 0, s3 = 0;
#pragma unroll
  for (int sl = 0; sl < 4; ++sl) {
    const uint2 u = *(const uint2*)(P + (((long)(b * 4 + sl)) << 20) + ((long)j << 2));
    s0 += h2f(u.x & 0xffff); s1 += h2f(u.x >> 16);
    s2 += h2f(u.y & 0xffff); s3 += h2f(u.y >> 16);
  }
  unsigned short o4[4] = {f2h(s0), f2h(s1), f2h(s2), f2h(s3)};
  *(uint2*)(O + ((long)b << 20) + ((long)j << 2)) = *(const uint2*)o4;
}

// ---------------------------------------------------------------------------
extern "C" void kernel_launch(void* const* d_in, const int* in_sizes, int n_in,
                              void* d_out, int out_size, void* d_ws, size_t ws_size,
                              hipStream_t stream) {
  const float* q  = (const float*)d_in[0];
  const float* k  = (const float*)d_in[1];
  const float* v  = (const float*)d_in[2];
  const float* Wq = (const float*)d_in[3];
  const float* bq = (const float*)d_in[4];
  const float* Wk = (const float*)d_in[5];
  const float* bk = (const float*)d_in[6];
  const float* Wv = (const float*)d_in[7];
  const float* bv = (const float*)d_in[8];
  const float* Wo = (const float*)d_in[9];
  const float* bo = (const float*)d_in[10];
  float* out = (float*)d_out;

  // workspace layout (~150 MB)
  char* p = (char*)d_ws;
  unsigned short* Part = (unsigned short*)p; p += 33554432;   // fp16 [16][1024][1024]
  unsigned short* WqT = (unsigned short*)p;  p += 2097152;
  unsigned short* WkT = (unsigned short*)p;  p += 2097152;
  unsigned short* WvT = (unsigned short*)p;  p += 2097152;
  unsigned short* WoT = (unsigned short*)p;  p += 2097152;
  unsigned short* Eq  = (unsigned short*)p;  p += 33554432;   // fp16 [4][4096][1024]
  unsigned short* ETk = (unsigned short*)p;  p += 33554432;   // fp16 [4][1024][4096]
  unsigned short* ETv = (unsigned short*)p;  p += 33554432;
  unsigned short* Mh  = (unsigned short*)p;  p += 8388608;    // fp16 [4][1024][1024]
  unsigned short* GTh = (unsigned short*)p;  p += 8388608;    // fp16 [4][1024][1024]
  float* sinvq = (float*)p; p += 16384 * 4;
  float* sk    = (float*)p; p += 4096 * 4;
  float* sv    = (float*)p; p += 4096 * 4;

  const dim3 blk(256);
  const dim3 blk512(512);
  const long S22 = 4096L * 1024;   // 2^22
  const long S20 = 1024L * 1024;   // 2^20

  // weights -> fp16 transposed
  w_trh<<<dim3(16, 16), blk, 0, stream>>>(Wq, WqT);
  w_trh<<<dim3(16, 16), blk, 0, stream>>>(Wk, WkT);
  w_trh<<<dim3(16, 16), blk, 0, stream>>>(Wv, WvT);
  w_trh<<<dim3(16, 16), blk, 0, stream>>>(Wo, WoT);

  // ---- Q path: Eq = exp(q@Wq + bq) (fp32 A, fused cvt); sinvq = 1/rowsum
  gemmt<1, 3><<<512, blk512, 0, stream>>>(q, WqT, Eq, bq, nullptr,
      1024, 1024, 1024, 4, 32, 1, S22, 0, S22);
  rsum_inv_1k<<<16384, blk, 0, stream>>>(Eq, sinvq);

  // ---- K path: ETk[b][d][l] = exp(k@Wk + bk)^T ; sk = 1/colsum
  gemmt<1, 4><<<512, blk512, 0, stream>>>(k, WkT, ETk, bk, nullptr,
      1024, 1024, 1024, 4, 32, 1, S22, 0, S22);
  rsum_inv_4k<<<4096, blk, 0, stream>>>(ETk, sk);

  // ---- V path
  gemmt<1, 4><<<512, blk512, 0, stream>>>(v, WvT, ETv, bv, nullptr,
      1024, 1024, 1024, 4, 32, 1, S22, 0, S22);
  rsum_inv_4k<<<4096, blk, 0, stream>>>(ETv, sv);

  // ---- Mraw partials: P[b*4+s] = ETk_chunk @ ETv_chunk^T (K=4096 split x4)
  //      Mh = f16(red4(P) * sk[dk] * sv[dv])
  gemmt<0, 2><<<512, blk512, 0, stream>>>(ETk, ETv, Part, nullptr, nullptr,
      1024, 1024, 4096, 4, 8, 4, S22, S22, S20);
  red4m<<<4096, blk, 0, stream>>>(Part, sk, sv, Mh);

  // ---- GT_b = (M_b @ Wo)^T = WoT @ M_b^T : K=1024 split x4
  gemmt<0, 2><<<512, blk512, 0, stream>>>(WoT, Mh, Part, nullptr, nullptr,
      1024, 256, 1024, 4, 8, 4, 0, S20, S20);
  red4h<<<4096, blk, 0, stream>>>(Part, GTh);

  // ---- Out_b = diag(sinvq) * (Eq_b @ GT_b^T) + bo
  gemmt<0, 5><<<512, blk512, 0, stream>>>(Eq, GTh, out, bo, sinvq,
      1024, 1024, 1024, 4, 32, 1, S22, S20, S22);

  (void)in_sizes; (void)n_in; (void)out_size; (void)ws_size;
}